// Round 10
// baseline (394.625 us; speedup 1.0000x reference)
//
#include <hip/hip_runtime.h>
#include <hip/hip_bf16.h>
#include <stdint.h>

// ---------------------------------------------------------------------------
// ImageAttention (SAM-style, decomposed rel-pos) on MI355X / gfx950.
// Split-bf16 (hi+lo) MFMA for QKV/proj GEMMs and QK^T; P@V plain bf16.
// R8 (fix: removed stray "#pragma unroll 1" before epilogue if — compile
//   error in R9; logic unchanged): k_attn waves split over (q-half x
//   k-half) quadrants: each wave reads only HALF the K/V tile from LDS
//   (DS was ~86% of wall in R7). Per-wave online softmax over its k-half;
//   flash-combine across k-half waves in the epilogue via LDS. T14 async
//   staging kept (R7, +5%).
// k_gemm keeps R6's 2-phase counted-vmcnt pipeline.
// ---------------------------------------------------------------------------

typedef unsigned short u16;
typedef unsigned int   u32;
typedef __attribute__((ext_vector_type(8))) short s8v;   // 8 x bf16 (4 VGPR)
typedef __attribute__((ext_vector_type(4))) float f4v;   // MFMA acc / 16B ld
typedef __attribute__((ext_vector_type(4))) unsigned short us4;
typedef __attribute__((ext_vector_type(8))) unsigned short us8;
typedef __attribute__((ext_vector_type(2))) unsigned int u32x2;

#define DEVI static __device__ __forceinline__

constexpr int   NTOK   = 4096;
constexpr int   DM     = 768;
constexpr float LOG2E_F = 1.4426950408889634f;
constexpr float KSCALE  = 0.18033688011112042f;   // (1/8) * log2(e)

#if __has_builtin(__builtin_amdgcn_exp2f)
#define EXP2(x) __builtin_amdgcn_exp2f(x)
#else
#define EXP2(x) exp2f(x)
#endif

DEVI u16 f2bf(float x){
  u32 u = __builtin_bit_cast(u32, x);
  u32 r = (u + 0x7FFFu + ((u >> 16) & 1u)) >> 16;
  return (u16)r;
}
DEVI float bf2f(u16 h){
  u32 u = ((u32)h) << 16;
  return __builtin_bit_cast(float, u);
}
DEVI u32 cvtpk(float lo, float hi){   // dst.lo16 = bf16(lo), dst.hi16 = bf16(hi)
  u32 r;
  asm("v_cvt_pk_bf16_f32 %0, %1, %2" : "=v"(r) : "v"(lo), "v"(hi));
  return r;
}

typedef const __attribute__((address_space(1))) u32* gp1;
typedef __attribute__((address_space(3))) u32* lp3;
DEVI void gload_lds16(const void* g, void* l){
  __builtin_amdgcn_global_load_lds((gp1)g, (lp3)l, 16, 0, 0);
}

DEVI f4v MFMA16(s8v a, s8v b, f4v c){
  return __builtin_amdgcn_mfma_f32_16x16x32_bf16(a, b, c, 0, 0, 0);
}

// raw barrier with compiler fences (no vmcnt/lgkm drain!)
DEVI void hard_barrier(){
  __builtin_amdgcn_sched_barrier(0);
  asm volatile("" ::: "memory");
  __builtin_amdgcn_s_barrier();
  asm volatile("" ::: "memory");
  __builtin_amdgcn_sched_barrier(0);
}

// ------------------------------------------------------------------ split ---
__global__ void k_split(const float* __restrict__ in, u16* __restrict__ hi,
                        u16* __restrict__ lo, int n4){
  int i = blockIdx.x * blockDim.x + threadIdx.x;
  int stride = gridDim.x * blockDim.x;
  for (; i < n4; i += stride){
    f4v v = ((const f4v*)in)[i];
    us4 h, l;
#pragma unroll
    for (int j = 0; j < 4; ++j){
      u16 hb = f2bf(v[j]);
      h[j] = hb;
      l[j] = f2bf(v[j] - bf2f(hb));
    }
    ((us4*)hi)[i] = h;
    ((us4*)lo)[i] = l;
  }
}

// ------------------------------------------------------------- split GEMM ---
// C[M,N] = (Ah+Al)[M,K] @ (Bh+Bl)[N,K]^T, 128x128 tile, BK=32, 4 waves.
// Double-buffered LDS (2 x 32KB), 2-phase pipeline, counted vmcnt(8). (R6)
template<int EPI>
__global__ __launch_bounds__(256)
void k_gemm(const u16* __restrict__ Ah, const u16* __restrict__ Al,
            const u16* __restrict__ Bh, const u16* __restrict__ Bl,
            const float* __restrict__ bias, int K,
            u16* __restrict__ Qh, u16* __restrict__ Ql,
            u16* __restrict__ Kh, u16* __restrict__ Kl,
            float* __restrict__ Vf, float* __restrict__ Cout)
{
  __shared__ __align__(16) unsigned char sm[65536]; // 2 x (Ah|Al|Bh|Bl 8KB)
  const int t = threadIdx.x;
  const int lane = t & 63, wid = t >> 6;
  const int l15 = lane & 15, g = lane >> 4;
  const int wr = wid >> 1, wc = wid & 1;
  const int m0 = blockIdx.y * 128, n0 = blockIdx.x * 128;

  const char* aGh[2]; const char* aGl[2]; const char* bGh[2]; const char* bGl[2];
#pragma unroll
  for (int ch = 0; ch < 2; ++ch){
    int p = ch * 4096 + t * 16;
    int pair = p >> 7, w = p & 127;
    int u = w ^ ((pair & 7) << 4);
    int row = 2 * pair + (u >> 6);
    int cb  = u & 63;
    aGh[ch] = (const char*)Ah + (size_t)(m0 + row) * K * 2 + cb;
    aGl[ch] = (const char*)Al + (size_t)(m0 + row) * K * 2 + cb;
    bGh[ch] = (const char*)Bh + (size_t)(n0 + row) * K * 2 + cb;
    bGl[ch] = (const char*)Bl + (size_t)(n0 + row) * K * 2 + cb;
  }
  const int axor = ((l15 & 1) * 64 + g * 16) ^ (((l15 >> 1) & 7) << 4);
  const int abase = (wr * 32 + (l15 >> 1)) * 128 + axor;
  const int bbase = 16384 + (wc * 32 + (l15 >> 1)) * 128 + axor;

  // prologue: stage K-step 0 into buffer 0
#pragma unroll
  for (int ch = 0; ch < 2; ++ch){
    gload_lds16(aGh[ch], sm + 0     + ch*4096 + wid*1024);
    gload_lds16(aGl[ch], sm + 8192  + ch*4096 + wid*1024);
    gload_lds16(bGh[ch], sm + 16384 + ch*4096 + wid*1024);
    gload_lds16(bGl[ch], sm + 24576 + ch*4096 + wid*1024);
    aGh[ch] += 64; aGl[ch] += 64; bGh[ch] += 64; bGl[ch] += 64;
  }

  f4v acc[4][4] = {};
  const int KSTEPS = K >> 5;
  for (int kt = 0; kt < KSTEPS; ++kt){
    const int bb = (kt & 1) * 32768;
    if (kt + 1 < KSTEPS){
      const int nb = ((kt + 1) & 1) * 32768;
#pragma unroll
      for (int ch = 0; ch < 2; ++ch){
        gload_lds16(aGh[ch], sm + nb + 0     + ch*4096 + wid*1024);
        gload_lds16(aGl[ch], sm + nb + 8192  + ch*4096 + wid*1024);
        gload_lds16(bGh[ch], sm + nb + 16384 + ch*4096 + wid*1024);
        gload_lds16(bGl[ch], sm + nb + 24576 + ch*4096 + wid*1024);
        aGh[ch] += 64; aGl[ch] += 64; bGh[ch] += 64; bGl[ch] += 64;
      }
      asm volatile("s_waitcnt vmcnt(8)" ::: "memory");   // step kt landed
    } else {
      asm volatile("s_waitcnt vmcnt(0)" ::: "memory");
    }
    hard_barrier();

    s8v af[4][2];
#pragma unroll
    for (int mi = 0; mi < 4; ++mi){
      af[mi][0] = *(const s8v*)(sm + bb + abase + mi*1024);
      af[mi][1] = *(const s8v*)(sm + bb + abase + mi*1024 + 8192);
    }
    __builtin_amdgcn_s_setprio(1);
#pragma unroll
    for (int ni = 0; ni < 4; ++ni){
      s8v bh = *(const s8v*)(sm + bb + bbase + ni*1024);
      s8v bl = *(const s8v*)(sm + bb + bbase + ni*1024 + 8192);
#pragma unroll
      for (int mi = 0; mi < 4; ++mi){
        acc[mi][ni] = MFMA16(af[mi][0], bh, acc[mi][ni]);
        acc[mi][ni] = MFMA16(af[mi][0], bl, acc[mi][ni]);
        acc[mi][ni] = MFMA16(af[mi][1], bh, acc[mi][ni]);
      }
    }
    __builtin_amdgcn_s_setprio(0);
    hard_barrier();   // protect buf[kt&1] before restage at kt+2
  }

  if (EPI == 2){
#pragma unroll
    for (int ni = 0; ni < 4; ++ni){
      int col = n0 + wc*64 + ni*16 + l15;
      float bq = bias[col];
#pragma unroll
      for (int mi = 0; mi < 4; ++mi){
        int rw0 = m0 + wr*64 + mi*16 + g*4;
#pragma unroll
        for (int r = 0; r < 4; ++r)
          Cout[(size_t)(rw0 + r) * DM + col] = acc[mi][ni][r] + bq;
      }
    }
  } else {
#pragma unroll
    for (int ni = 0; ni < 4; ++ni){
      int colb = n0 + wc*64 + ni*16;        // tile never straddles 768/64 edges
      float bq = bias[colb + l15];
      int which = colb / DM;
      int rem   = colb % DM;
      int head  = rem >> 6;
      int c     = (rem & 63) + l15;
#pragma unroll
      for (int mi = 0; mi < 4; ++mi){
        int n = m0 + wr*64 + mi*16 + g*4;
#pragma unroll
        for (int r = 0; r < 4; ++r){
          float v = acc[mi][ni][r] + bq;
          size_t idx = ((size_t)head * NTOK + (n + r)) * 64 + c;
          if (which == 0){
            u16 hb = f2bf(v);
            Qh[idx] = hb; Ql[idx] = f2bf(v - bf2f(hb));
          } else if (which == 1){
            float v2 = v * KSCALE;            // fold softmax scale * log2(e)
            u16 hb = f2bf(v2);
            Kh[idx] = hb; Kl[idx] = f2bf(v2 - bf2f(hb));
          } else {
            Vf[idx] = v;
          }
        }
      }
    }
  }
}

// ------------------------------------------------------------ V transpose ---
// Vf [h][n][c] f32  ->  Vth [h][c][n] bf16 (hi only; PV is plain-bf16)
__global__ void k_vtrans(const float* __restrict__ Vf, u16* __restrict__ Vth){
  __shared__ float tile[64][65];
  int h = blockIdx.y, nt = blockIdx.x;
  int t = threadIdx.x;
  {
    int r = t >> 2, c0 = (t & 3) * 16;
    const float* src = Vf + ((size_t)h * NTOK + nt*64 + r) * 64 + c0;
#pragma unroll
    for (int j = 0; j < 4; ++j){
      f4v v = *(const f4v*)(src + j*4);
      tile[r][c0+j*4+0] = v[0]; tile[r][c0+j*4+1] = v[1];
      tile[r][c0+j*4+2] = v[2]; tile[r][c0+j*4+3] = v[3];
    }
  }
  __syncthreads();
  {
    int c = t >> 2, b = (t & 3) * 16;
    us8 o0, o1;
#pragma unroll
    for (int i = 0; i < 16; ++i){
      u16 bv = f2bf(tile[b + i][c]);
      if (i < 8) o0[i] = bv; else o1[i-8] = bv;
    }
    u16* dst = Vth + ((size_t)h * 64 + c) * NTOK + nt*64 + b;
    *(us8*)(dst)     = o0;
    *(us8*)(dst + 8) = o1;
  }
}

// --------------------------------------------------------- rel-pos einsums ---
__global__ void k_relh(const u16* __restrict__ Qh, const u16* __restrict__ Ql,
                       const float* __restrict__ rp, float* __restrict__ R){
  __shared__ float qs[64][68];
  __shared__ float rs[64][68];
  int h = blockIdx.y, qh = blockIdx.x;
  int t = threadIdx.x;
  {
    int r = t >> 2, c0 = (t & 3) * 16;
    size_t qb = ((size_t)h * NTOK + qh*64 + r) * 64 + c0;
#pragma unroll
    for (int j = 0; j < 2; ++j){
      us8 vh = *(const us8*)(Qh + qb + j*8);
      us8 vl = *(const us8*)(Ql + qb + j*8);
#pragma unroll
      for (int e = 0; e < 8; ++e)
        qs[r][c0 + j*8 + e] = bf2f(vh[e]) + bf2f(vl[e]);
    }
    const float* pr = rp + (size_t)(qh - r + 63) * 64 + c0;
#pragma unroll
    for (int j = 0; j < 4; ++j){
      f4v v = *(const f4v*)(pr + j*4);
      rs[r][c0+j*4+0]=v[0]; rs[r][c0+j*4+1]=v[1];
      rs[r][c0+j*4+2]=v[2]; rs[r][c0+j*4+3]=v[3];
    }
  }
  __syncthreads();
  int qw = t >> 2, k0 = t & 3;
  float acc[16] = {};
  for (int c = 0; c < 64; c += 4){
    f4v qv = *(const f4v*)(&qs[qw][c]);
#pragma unroll
    for (int i = 0; i < 16; ++i){
      f4v rv = *(const f4v*)(&rs[k0 + 4*i][c]);
      acc[i] += qv[0]*rv[0] + qv[1]*rv[1] + qv[2]*rv[2] + qv[3]*rv[3];
    }
  }
  float* o = R + ((size_t)h * NTOK + qh*64 + qw) * 64;
#pragma unroll
  for (int i = 0; i < 16; ++i) o[k0 + 4*i] = acc[i] * LOG2E_F;
}

__global__ void k_relw(const u16* __restrict__ Qh, const u16* __restrict__ Ql,
                       const float* __restrict__ rp, float* __restrict__ R){
  __shared__ float qs[64][68];   // [qh][c]
  __shared__ float rs[64][68];   // [kw][c]
  int h = blockIdx.y, qw = blockIdx.x;
  int t = threadIdx.x;
  {
    int r = t >> 2, c0 = (t & 3) * 16;
    size_t qb = ((size_t)h * NTOK + r*64 + qw) * 64 + c0;
#pragma unroll
    for (int j = 0; j < 2; ++j){
      us8 vh = *(const us8*)(Qh + qb + j*8);
      us8 vl = *(const us8*)(Ql + qb + j*8);
#pragma unroll
      for (int e = 0; e < 8; ++e)
        qs[r][c0 + j*8 + e] = bf2f(vh[e]) + bf2f(vl[e]);
    }
    const float* pr = rp + (size_t)(qw - r + 63) * 64 + c0;
#pragma unroll
    for (int j = 0; j < 4; ++j){
      f4v v = *(const f4v*)(pr + j*4);
      rs[r][c0+j*4+0]=v[0]; rs[r][c0+j*4+1]=v[1];
      rs[r][c0+j*4+2]=v[2]; rs[r][c0+j*4+3]=v[3];
    }
  }
  __syncthreads();
  int qh = t >> 2, k0 = t & 3;
  float acc[16] = {};
  for (int c = 0; c < 64; c += 4){
    f4v qv = *(const f4v*)(&qs[qh][c]);
#pragma unroll
    for (int i = 0; i < 16; ++i){
      f4v rv = *(const f4v*)(&rs[k0 + 4*i][c]);
      acc[i] += qv[0]*rv[0] + qv[1]*rv[1] + qv[2]*rv[2] + qv[3]*rv[3];
    }
  }
  float* o = R + ((size_t)h * NTOK + qh*64 + qw) * 64;
#pragma unroll
  for (int i = 0; i < 16; ++i) o[k0 + 4*i] = acc[i] * LOG2E_F;
}

// --------------------------------------------------------- flash attention ---
// grid (64 q-tiles, 12 heads), 4 waves, KV tile = 64.
// R8 quadrant split: wave (qh_w = wid&1, kh_w = wid>>1) computes the
// 32q x 32k quadrant of each S-tile -> each wave reads only HALF of K/V.
// Per-wave online softmax over its k-half; flash-combine epilogue via LDS.
// SWAPPED operands: S^T = mfma(K, Q); lane (l15,g) owns q = qg*16+l15 for
// qg in {0,1}, k = kh_w*32 + kg*16 + 4g + r.
// T14 async staging (single buffer) as R7.
// LDS: Kh[8K]@0, Kl@8192, Vt@16384 (xor ((row&7)<<4));
//      P per wave @24576 + wid*2560 : [32 q][64B k] stride 80.
//      Epilogue combine reuses [0, 17920).
__global__ __launch_bounds__(256)
void k_attn(const u16* __restrict__ Qh, const u16* __restrict__ Ql,
            const u16* __restrict__ Kh, const u16* __restrict__ Kl,
            const u16* __restrict__ Vth,
            const float* __restrict__ Rh, const float* __restrict__ Rw,
            u16* __restrict__ Oh, u16* __restrict__ Ol)
{
  __shared__ __align__(16) unsigned char sm[34816];
  const int t = threadIdx.x;
  const int lane = t & 63, wid = t >> 6;
  const int l15 = lane & 15, g = lane >> 4;
  const int h = blockIdx.y;
  const int qh_w = wid & 1;       // q-half of this wave
  const int kh_w = wid >> 1;      // k-half of this wave
  const int qtile = blockIdx.x * 64;

  // staging pointers (xor-swizzled source, linear LDS dest = ch*4096 + t*16)
  const char* kGh[2]; const char* kGl[2]; const char* vG[2];
#pragma unroll
  for (int ch = 0; ch < 2; ++ch){
    int p = ch * 4096 + t * 16;
    int row = p >> 7;
    int cb  = (p & 127) ^ ((row & 7) << 4);
    kGh[ch] = (const char*)Kh + ((size_t)h * NTOK + row) * 128 + cb;
    kGl[ch] = (const char*)Kl + ((size_t)h * NTOK + row) * 128 + cb;
    vG[ch]  = (const char*)Vth + ((size_t)h * 64 + row) * (NTOK*2) + cb;
  }

  // Q fragments: qg in {0,1}; q = qtile + qh_w*32 + qg*16 + l15
  s8v qfh[2][2], qfl[2][2];
#pragma unroll
  for (int qg = 0; qg < 2; ++qg){
    const size_t qoff =
      ((size_t)h * NTOK + qtile + qh_w*32 + qg*16 + l15) * 64 + g * 8;
    qfh[qg][0] = *(const s8v*)(Qh + qoff);
    qfh[qg][1] = *(const s8v*)(Qh + qoff + 32);
    qfl[qg][0] = *(const s8v*)(Ql + qoff);
    qfl[qg][1] = *(const s8v*)(Ql + qoff + 32);
  }

  // K LDS read bases: kg in {0,1}, row = kh_w*32 + kg*16 + l15
  const int xr = (l15 & 7) << 4;
  int kb[2][2];
#pragma unroll
  for (int kg = 0; kg < 2; ++kg){
    int rl = kh_w*32 + kg*16 + l15;
    kb[kg][0] = rl*128 + ((g*16)      ^ xr);
    kb[kg][1] = rl*128 + ((g*16 + 64) ^ xr);
  }
  // V bases: dt in {0..3}, row = dt*16 + l15, k-bytes (kh_w*64 + 16g) ^ xr
  int vb[4];
#pragma unroll
  for (int dt = 0; dt < 4; ++dt)
    vb[dt] = 16384 + (dt*16 + l15)*128 + ((kh_w*64 + g*16) ^ xr);

  // P buffer: wave-private, [32 q][32 k bf16], row stride 80
  const int preg = 24576 + wid * 2560;

  // rel bias: rwv[kg][qg] = Rw[q][kh_w*32 + kg*16 + 4g .. +4]
  f4v rwv[2][2];
  const float* rhp[2];
#pragma unroll
  for (int qg = 0; qg < 2; ++qg){
    int q = qtile + qh_w*32 + qg*16 + l15;
    const float* base = Rw + ((size_t)h * NTOK + q) * 64 + kh_w*32 + 4*g;
    rwv[0][qg] = *(const f4v*)(base);
    rwv[1][qg] = *(const f4v*)(base + 16);
    rhp[qg] = Rh + ((size_t)h * NTOK + q) * 64;
  }

  // T14 reg-staged tile: 6 x 16B per thread
  f4v st[6];
  auto do_loads = [&](){
    st[0] = *(const f4v*)kGh[0]; st[1] = *(const f4v*)kGh[1];
    st[2] = *(const f4v*)kGl[0]; st[3] = *(const f4v*)kGl[1];
    st[4] = *(const f4v*)vG[0];  st[5] = *(const f4v*)vG[1];
    kGh[0] += 8192; kGh[1] += 8192;
    kGl[0] += 8192; kGl[1] += 8192;
    vG[0]  += 128;  vG[1]  += 128;
  };
  auto do_writes = [&](){
    *(f4v*)(sm + 0     +    0 + t*16) = st[0];
    *(f4v*)(sm + 0     + 4096 + t*16) = st[1];
    *(f4v*)(sm + 8192  +    0 + t*16) = st[2];
    *(f4v*)(sm + 8192  + 4096 + t*16) = st[3];
    *(f4v*)(sm + 16384 +    0 + t*16) = st[4];
    *(f4v*)(sm + 16384 + 4096 + t*16) = st[5];
  };

  // prologue: tile 0 -> LDS; tile 1 loads in flight
  do_loads();
  do_writes();
  do_loads();
  asm volatile("s_waitcnt lgkmcnt(0)" ::: "memory");
  hard_barrier();

  f4v o[4][2] = {};                 // o[dt][qg]: O[q][d=16dt+4g+r] partial
  float m2[2] = {-1.0e30f, -1.0e30f}, ls[2] = {0.f, 0.f};

  for (int it = 0; it < 64; ++it){
    float rhv[2];
    rhv[0] = rhp[0][it];
    rhv[1] = rhp[1][it];

    // S^T quadrant: s[kg][qg][r] = S[k = kh_w*32+kg*16+4g+r][q = qg*16+l15]
    f4v s[2][2];
    __builtin_amdgcn_s_setprio(1);
#pragma unroll
    for (int kg = 0; kg < 2; ++kg){
      s8v kh0 = *(const s8v*)(sm + kb[kg][0]);
      s8v kh1 = *(const s8v*)(sm + kb[kg][1]);
      s8v kl0 = *(const s8v*)(sm + kb[kg][0] + 8192);
      s8v kl1 = *(const s8v*)(sm + kb[kg][1] + 8192);
#pragma unroll
      for (int qg = 0; qg < 2; ++qg){
        f4v a = {};
        a = MFMA16(kh0, qfh[qg][0], a);
        a = MFMA16(kh1, qfh[qg][1], a);
        a = MFMA16(kl0, qfh[qg][0], a);
        a = MFMA16(kl1, qfh[qg][1], a);
        a = MFMA16(kh0, qfl[qg][0], a);
        a = MFMA16(kh1, qfl[qg][1], a);
        s[kg][qg] = a;
      }
    }
    __builtin_amdgcn_s_setprio(0);

    // bias + per-q partial max (k-half only)
    float pm[2] = {-1.0e30f, -1.0e30f};
#pragma unroll
    for (int kg = 0; kg < 2; ++kg){
#pragma unroll
      for (int qg = 0; qg < 2; ++qg){
#pragma unroll
        for (int r = 0; r < 4; ++r){
          s[kg][qg][r] += rhv[qg] + rwv[kg][qg][r];
          pm[qg] = fmaxf(pm[qg], s[kg][qg][r]);
        }
      }
    }
#pragma unroll
    for (int qg = 0; qg < 2; ++qg){
      pm[qg] = fmaxf(pm[qg], __shfl_xor(pm[qg], 16, 64));
      pm[qg] = fmaxf(pm[qg], __shfl_xor(pm[qg], 32, 64));
    }
    float fr[2];
#pragma unroll
    for (int qg = 0; qg < 2; ++qg){
      float mn = fmaxf(m2[qg], pm[qg]);
      fr[qg] = EXP2(m2[qg] - mn);
      m2[qg] = mn;
    }
    float ps[2] = {0.f, 0.f};
#pragma unroll
    for (int kg = 0; kg < 2; ++kg){
#pragma unroll
      for (int qg = 0; qg < 2; ++qg){
#pragma unroll
        for (int r = 0; r < 4; ++r){
          float p = EXP2(s[kg][qg][r] - m2[qg]);
          s[kg][qg][r] = p;
          ps[qg] += p;
        }
      }
    }
#pragma unroll
    for (int qg = 0; qg < 2; ++qg){
      ps[qg] += __shfl_xor(ps[qg], 16, 64);
      ps[qg] += __shfl_xor(ps[qg], 32, 64);
      ls[qg] = ls[qg] * fr[qg] + ps[qg];
    }

    // P -> LDS (wave-private): row q-local = qg*16+l15, k-byte = kg*32 + 8g
#pragma unroll
    for (int qg = 0; qg < 2; ++qg){
#pragma unroll
      for (int kg = 0; kg < 2; ++kg){
        u32x2 w2;
        w2[0] = cvtpk(s[kg][qg][0], s[kg][qg][1]);
        w2[1] = cvtpk(s[kg][qg][2], s[kg][qg][3]);
        *(u32x2*)(sm + preg + (qg*16 + l15)*80 + kg*32 + 8*g) = w2;
      }
    }
    // rescale O
#pragma unroll
    for (int dt = 0; dt < 4; ++dt){
#pragma unroll
      for (int qg = 0; qg < 2; ++qg){
#pragma unroll
        for (int r = 0; r < 4; ++r) o[dt][qg][r] *= fr[qg];
      }
    }
    // O^T partial += Vt(k-half) @ P^T : B = P[q][k=8g..8g+8]
    s8v pa0 = *(const s8v*)(sm + preg + l15*80        + 16*g);
    s8v pa1 = *(const s8v*)(sm + preg + (16+l15)*80   + 16*g);
    __builtin_amdgcn_s_setprio(1);
#pragma unroll
    for (int dt = 0; dt < 4; ++dt){
      s8v vf = *(const s8v*)(sm + vb[dt]);
      o[dt][0] = MFMA16(vf, pa0, o[dt][0]);
      o[dt][1] = MFMA16(vf, pa1, o[dt][1]);
    }
    __builtin_amdgcn_s_setprio(0);

    hard_barrier();          // A: all waves done reading tile it
    if (it < 63){
      do_writes();           // tile it+1 -> LDS (compiler waits the loads)
      if (it < 62) do_loads();   // tile it+2 -> regs, in flight across B
    }
    asm volatile("s_waitcnt lgkmcnt(0)" ::: "memory");
    hard_barrier();          // B: writes visible to all waves
  }

  // ----- epilogue: flash-combine across k-half partner waves via LDS -----
  // (after final barrier B all K/V/P LDS is dead; reuse [0, 17920))
  // per qh: O' [32 q][272B] at qh*8704 ; m/l at 17408 + qh*256 + qloc*8
  if (kh_w == 1){
#pragma unroll
    for (int qg = 0; qg < 2; ++qg){
#pragma unroll
      for (int dt = 0; dt < 4; ++dt)
        *(f4v*)(sm + qh_w*8704 + (qg*16 + l15)*272 + dt*64 + 16*g) = o[dt][qg];
      if (g == 0){
        *(float*)(sm + 17408 + qh_w*256 + (qg*16 + l15)*8)     = m2[qg];
        *(float*)(sm + 17408 + qh_w*256 + (qg*16 + l15)*8 + 4) = ls[qg];
      }
    }
  }
  asm volatile("s_waitcnt lgkmcnt(0)" ::: "memory");
  hard_barrier();
  if (kh_w == 0){
    float ai[2], bi[2];
#pragma unroll
    for (int qg = 0; qg < 2; ++qg){
      float mp = *(const float*)(sm + 17408 + qh_w*256 + (qg*16 + l15)*8);
      float lp = *(const float*)(sm + 17408 + qh_w*256 + (qg*16 + l15)*8 + 4);
      float M  = fmaxf(m2[qg], mp);
      float a  = EXP2(m2[qg] - M);
      float b  = EXP2(mp - M);
      float inv = 1.0f / (a*ls[qg] + b*lp);
      ai[qg] = a * inv; bi[qg] = b * inv;
    }
#pragma unroll
    for (int qg = 0; qg < 2; ++qg){
      const size_t obase =
        (size_t)(qtile + qh_w*32 + qg*16 + l15) * DM + h*64 + 4*g;
#pragma unroll
      for (int dt = 0; dt < 4; ++dt){
        f4v op = *(const f4v*)(sm + qh_w*8704 + (qg*16 + l15)*272 + dt*64 + 16*g);
        us4 hv, lv;
#pragma unroll
        for (int r = 0; r < 4; ++r){
          float v = o[dt][qg][r] * ai[qg] + op[r] * bi[qg];
          u16 hb = f2bf(v);
          hv[r] = hb;
          lv[r] = f2bf(v - bf2f(hb));
        }
        *(us4*)(Oh + obase + 16*dt) = hv;
        *(us4*)(Ol + obase + 16*dt) = lv;
      }
    }
  }
}

// ------------------------------------------------------------------- host ---
extern "C" void kernel_launch(void* const* d_in, const int* in_sizes, int n_in,
                              void* d_out, int out_size, void* d_ws, size_t ws_size,
                              hipStream_t stream){
  (void)in_sizes; (void)n_in; (void)out_size; (void)ws_size;
  const float* x      = (const float*)d_in[0];
  const float* w_qkv  = (const float*)d_in[1];
  const float* b_qkv  = (const float*)d_in[2];
  const float* w_proj = (const float*)d_in[3];
  const float* b_proj = (const float*)d_in[4];
  const float* rph    = (const float*)d_in[5];
  const float* rpw    = (const float*)d_in[6];
  float* out = (float*)d_out;

  char* w = (char*)d_ws;
  size_t off = 0;
  auto nxt = [&](size_t b) -> char* {
    char* p = w + off; off += (b + 255) & ~(size_t)255; return p;
  };
  u16*   Xh  = (u16*)  nxt((size_t)NTOK*DM*2);
  u16*   Xl  = (u16*)  nxt((size_t)NTOK*DM*2);
  u16*   Wqh = (u16*)  nxt((size_t)3*DM*DM*2);
  u16*   Wql = (u16*)  nxt((size_t)3*DM*DM*2);
  u16*   Wph = (u16*)  nxt((size_t)DM*DM*2);
  u16*   Wpl = (u16*)  nxt((size_t)DM*DM*2);
  u16*   Qh  = (u16*)  nxt((size_t)NTOK*DM*2);
  u16*   Ql  = (u16*)  nxt((size_t)NTOK*DM*2);
  u16*   Kh  = (u16*)  nxt((size_t)NTOK*DM*2);
  u16*   Kl  = (u16*)  nxt((size_t)NTOK*DM*2);
  float* Vf  = (float*)nxt((size_t)NTOK*DM*4);
  u16*   Vth = (u16*)  nxt((size_t)NTOK*DM*2);
  float* Rh  = (float*)nxt((size_t)12*NTOK*64*4);
  float* Rw  = (float*)nxt((size_t)12*NTOK*64*4);
  u16*   Oh  = Xh;                                    // X dead after G1
  u16*   Ol  = Xl;

  k_split<<<dim3(3072), dim3(256), 0, stream>>>(x,      Xh,  Xl,  NTOK*DM/4);
  k_split<<<dim3(1728), dim3(256), 0, stream>>>(w_qkv,  Wqh, Wql, 3*DM*DM/4);
  k_split<<<dim3(576),  dim3(256), 0, stream>>>(w_proj, Wph, Wpl, DM*DM/4);

  k_gemm<1><<<dim3(18, 32), dim3(256), 0, stream>>>(
      Xh, Xl, Wqh, Wql, b_qkv, DM, Qh, Ql, Kh, Kl, Vf, nullptr);

  k_vtrans<<<dim3(64, 12), dim3(256), 0, stream>>>(Vf, Vth);
  k_relh  <<<dim3(64, 12), dim3(256), 0, stream>>>(Qh, Ql, rph, Rh);
  k_relw  <<<dim3(64, 12), dim3(256), 0, stream>>>(Qh, Ql, rpw, Rw);

  k_attn<<<dim3(64, 12), dim3(256), 0, stream>>>(Qh, Ql, Kh, Kl, Vth, Rh, Rw, Oh, Ol);

  k_gemm<2><<<dim3(6, 32), dim3(256), 0, stream>>>(
      Oh, Ol, Wph, Wpl, b_proj, DM,
      nullptr, nullptr, nullptr, nullptr, nullptr, out);
}

// Round 11
// 351.536 us; speedup vs baseline: 1.1226x; 1.1226x over previous
//
#include <hip/hip_runtime.h>
#include <hip/hip_bf16.h>
#include <stdint.h>

// ---------------------------------------------------------------------------
// ImageAttention (SAM-style, decomposed rel-pos) on MI355X / gfx950.
// Split-bf16 (hi+lo) MFMA for QKV/proj GEMMs and QK^T; P@V plain bf16.
// R11: REVERT k_attn to R7 structure (R10 quadrant split regressed 161->215:
//   uniform utilization drop => MFMA-chain serialization, H1). Two changes:
//   (1) QK^T 6-deep chains split into 2x3 (8 independent chains) to test H1;
//   (2) three k_split launches merged into one k_split3 (9->7 dispatches).
// k_gemm keeps R6's 2-phase counted-vmcnt pipeline; T14 staging kept in attn.
// ---------------------------------------------------------------------------

typedef unsigned short u16;
typedef unsigned int   u32;
typedef __attribute__((ext_vector_type(8))) short s8v;   // 8 x bf16 (4 VGPR)
typedef __attribute__((ext_vector_type(4))) float f4v;   // MFMA acc / 16B ld
typedef __attribute__((ext_vector_type(4))) unsigned short us4;
typedef __attribute__((ext_vector_type(8))) unsigned short us8;
typedef __attribute__((ext_vector_type(2))) unsigned int u32x2;

#define DEVI static __device__ __forceinline__

constexpr int   NTOK   = 4096;
constexpr int   DM     = 768;
constexpr float LOG2E_F = 1.4426950408889634f;
constexpr float KSCALE  = 0.18033688011112042f;   // (1/8) * log2(e)

#if __has_builtin(__builtin_amdgcn_exp2f)
#define EXP2(x) __builtin_amdgcn_exp2f(x)
#else
#define EXP2(x) exp2f(x)
#endif

DEVI u16 f2bf(float x){
  u32 u = __builtin_bit_cast(u32, x);
  u32 r = (u + 0x7FFFu + ((u >> 16) & 1u)) >> 16;
  return (u16)r;
}
DEVI float bf2f(u16 h){
  u32 u = ((u32)h) << 16;
  return __builtin_bit_cast(float, u);
}
DEVI u32 cvtpk(float lo, float hi){   // dst.lo16 = bf16(lo), dst.hi16 = bf16(hi)
  u32 r;
  asm("v_cvt_pk_bf16_f32 %0, %1, %2" : "=v"(r) : "v"(lo), "v"(hi));
  return r;
}

typedef const __attribute__((address_space(1))) u32* gp1;
typedef __attribute__((address_space(3))) u32* lp3;
DEVI void gload_lds16(const void* g, void* l){
  __builtin_amdgcn_global_load_lds((gp1)g, (lp3)l, 16, 0, 0);
}

DEVI f4v MFMA16(s8v a, s8v b, f4v c){
  return __builtin_amdgcn_mfma_f32_16x16x32_bf16(a, b, c, 0, 0, 0);
}

// raw barrier with compiler fences (no vmcnt/lgkm drain!)
DEVI void hard_barrier(){
  __builtin_amdgcn_sched_barrier(0);
  asm volatile("" ::: "memory");
  __builtin_amdgcn_s_barrier();
  asm volatile("" ::: "memory");
  __builtin_amdgcn_sched_barrier(0);
}

// ---------------------------------------------------------------- split3 ---
// One launch for all three f32 -> (bf16 hi, bf16 lo) splits.
__global__ void k_split3(const float* __restrict__ x,  u16* __restrict__ xh,
                         u16* __restrict__ xl,  int n0,
                         const float* __restrict__ w1, u16* __restrict__ w1h,
                         u16* __restrict__ w1l, int n1,
                         const float* __restrict__ w2, u16* __restrict__ w2h,
                         u16* __restrict__ w2l, int n2){
  int i = blockIdx.x * blockDim.x + threadIdx.x;
  int stride = gridDim.x * blockDim.x;
  const int tot = n0 + n1 + n2;
  for (; i < tot; i += stride){
    const float* src; u16* dh; u16* dl; int j;
    if (i < n0)           { src = x;  dh = xh;  dl = xl;  j = i; }
    else if (i < n0 + n1) { src = w1; dh = w1h; dl = w1l; j = i - n0; }
    else                  { src = w2; dh = w2h; dl = w2l; j = i - n0 - n1; }
    f4v v = ((const f4v*)src)[j];
    us4 h, l;
#pragma unroll
    for (int e = 0; e < 4; ++e){
      u16 hb = f2bf(v[e]);
      h[e] = hb;
      l[e] = f2bf(v[e] - bf2f(hb));
    }
    ((us4*)dh)[j] = h;
    ((us4*)dl)[j] = l;
  }
}

// ------------------------------------------------------------- split GEMM ---
// C[M,N] = (Ah+Al)[M,K] @ (Bh+Bl)[N,K]^T, 128x128 tile, BK=32, 4 waves.
// Double-buffered LDS (2 x 32KB), 2-phase pipeline, counted vmcnt(8). (R6)
template<int EPI>
__global__ __launch_bounds__(256)
void k_gemm(const u16* __restrict__ Ah, const u16* __restrict__ Al,
            const u16* __restrict__ Bh, const u16* __restrict__ Bl,
            const float* __restrict__ bias, int K,
            u16* __restrict__ Qh, u16* __restrict__ Ql,
            u16* __restrict__ Kh, u16* __restrict__ Kl,
            float* __restrict__ Vf, float* __restrict__ Cout)
{
  __shared__ __align__(16) unsigned char sm[65536]; // 2 x (Ah|Al|Bh|Bl 8KB)
  const int t = threadIdx.x;
  const int lane = t & 63, wid = t >> 6;
  const int l15 = lane & 15, g = lane >> 4;
  const int wr = wid >> 1, wc = wid & 1;
  const int m0 = blockIdx.y * 128, n0 = blockIdx.x * 128;

  const char* aGh[2]; const char* aGl[2]; const char* bGh[2]; const char* bGl[2];
#pragma unroll
  for (int ch = 0; ch < 2; ++ch){
    int p = ch * 4096 + t * 16;
    int pair = p >> 7, w = p & 127;
    int u = w ^ ((pair & 7) << 4);
    int row = 2 * pair + (u >> 6);
    int cb  = u & 63;
    aGh[ch] = (const char*)Ah + (size_t)(m0 + row) * K * 2 + cb;
    aGl[ch] = (const char*)Al + (size_t)(m0 + row) * K * 2 + cb;
    bGh[ch] = (const char*)Bh + (size_t)(n0 + row) * K * 2 + cb;
    bGl[ch] = (const char*)Bl + (size_t)(n0 + row) * K * 2 + cb;
  }
  const int axor = ((l15 & 1) * 64 + g * 16) ^ (((l15 >> 1) & 7) << 4);
  const int abase = (wr * 32 + (l15 >> 1)) * 128 + axor;
  const int bbase = 16384 + (wc * 32 + (l15 >> 1)) * 128 + axor;

  // prologue: stage K-step 0 into buffer 0
#pragma unroll
  for (int ch = 0; ch < 2; ++ch){
    gload_lds16(aGh[ch], sm + 0     + ch*4096 + wid*1024);
    gload_lds16(aGl[ch], sm + 8192  + ch*4096 + wid*1024);
    gload_lds16(bGh[ch], sm + 16384 + ch*4096 + wid*1024);
    gload_lds16(bGl[ch], sm + 24576 + ch*4096 + wid*1024);
    aGh[ch] += 64; aGl[ch] += 64; bGh[ch] += 64; bGl[ch] += 64;
  }

  f4v acc[4][4] = {};
  const int KSTEPS = K >> 5;
  for (int kt = 0; kt < KSTEPS; ++kt){
    const int bb = (kt & 1) * 32768;
    if (kt + 1 < KSTEPS){
      const int nb = ((kt + 1) & 1) * 32768;
#pragma unroll
      for (int ch = 0; ch < 2; ++ch){
        gload_lds16(aGh[ch], sm + nb + 0     + ch*4096 + wid*1024);
        gload_lds16(aGl[ch], sm + nb + 8192  + ch*4096 + wid*1024);
        gload_lds16(bGh[ch], sm + nb + 16384 + ch*4096 + wid*1024);
        gload_lds16(bGl[ch], sm + nb + 24576 + ch*4096 + wid*1024);
        aGh[ch] += 64; aGl[ch] += 64; bGh[ch] += 64; bGl[ch] += 64;
      }
      asm volatile("s_waitcnt vmcnt(8)" ::: "memory");   // step kt landed
    } else {
      asm volatile("s_waitcnt vmcnt(0)" ::: "memory");
    }
    hard_barrier();

    s8v af[4][2];
#pragma unroll
    for (int mi = 0; mi < 4; ++mi){
      af[mi][0] = *(const s8v*)(sm + bb + abase + mi*1024);
      af[mi][1] = *(const s8v*)(sm + bb + abase + mi*1024 + 8192);
    }
    __builtin_amdgcn_s_setprio(1);
#pragma unroll
    for (int ni = 0; ni < 4; ++ni){
      s8v bh = *(const s8v*)(sm + bb + bbase + ni*1024);
      s8v bl = *(const s8v*)(sm + bb + bbase + ni*1024 + 8192);
#pragma unroll
      for (int mi = 0; mi < 4; ++mi){
        acc[mi][ni] = MFMA16(af[mi][0], bh, acc[mi][ni]);
        acc[mi][ni] = MFMA16(af[mi][0], bl, acc[mi][ni]);
        acc[mi][ni] = MFMA16(af[mi][1], bh, acc[mi][ni]);
      }
    }
    __builtin_amdgcn_s_setprio(0);
    hard_barrier();   // protect buf[kt&1] before restage at kt+2
  }

  if (EPI == 2){
#pragma unroll
    for (int ni = 0; ni < 4; ++ni){
      int col = n0 + wc*64 + ni*16 + l15;
      float bq = bias[col];
#pragma unroll
      for (int mi = 0; mi < 4; ++mi){
        int rw0 = m0 + wr*64 + mi*16 + g*4;
#pragma unroll
        for (int r = 0; r < 4; ++r)
          Cout[(size_t)(rw0 + r) * DM + col] = acc[mi][ni][r] + bq;
      }
    }
  } else {
#pragma unroll
    for (int ni = 0; ni < 4; ++ni){
      int colb = n0 + wc*64 + ni*16;        // tile never straddles 768/64 edges
      float bq = bias[colb + l15];
      int which = colb / DM;
      int rem   = colb % DM;
      int head  = rem >> 6;
      int c     = (rem & 63) + l15;
#pragma unroll
      for (int mi = 0; mi < 4; ++mi){
        int n = m0 + wr*64 + mi*16 + g*4;
#pragma unroll
        for (int r = 0; r < 4; ++r){
          float v = acc[mi][ni][r] + bq;
          size_t idx = ((size_t)head * NTOK + (n + r)) * 64 + c;
          if (which == 0){
            u16 hb = f2bf(v);
            Qh[idx] = hb; Ql[idx] = f2bf(v - bf2f(hb));
          } else if (which == 1){
            float v2 = v * KSCALE;            // fold softmax scale * log2(e)
            u16 hb = f2bf(v2);
            Kh[idx] = hb; Kl[idx] = f2bf(v2 - bf2f(hb));
          } else {
            Vf[idx] = v;
          }
        }
      }
    }
  }
}

// ------------------------------------------------------------ V transpose ---
// Vf [h][n][c] f32  ->  Vth [h][c][n] bf16 (hi only; PV is plain-bf16)
__global__ void k_vtrans(const float* __restrict__ Vf, u16* __restrict__ Vth){
  __shared__ float tile[64][65];
  int h = blockIdx.y, nt = blockIdx.x;
  int t = threadIdx.x;
  {
    int r = t >> 2, c0 = (t & 3) * 16;
    const float* src = Vf + ((size_t)h * NTOK + nt*64 + r) * 64 + c0;
#pragma unroll
    for (int j = 0; j < 4; ++j){
      f4v v = *(const f4v*)(src + j*4);
      tile[r][c0+j*4+0] = v[0]; tile[r][c0+j*4+1] = v[1];
      tile[r][c0+j*4+2] = v[2]; tile[r][c0+j*4+3] = v[3];
    }
  }
  __syncthreads();
  {
    int c = t >> 2, b = (t & 3) * 16;
    us8 o0, o1;
#pragma unroll
    for (int i = 0; i < 16; ++i){
      u16 bv = f2bf(tile[b + i][c]);
      if (i < 8) o0[i] = bv; else o1[i-8] = bv;
    }
    u16* dst = Vth + ((size_t)h * 64 + c) * NTOK + nt*64 + b;
    *(us8*)(dst)     = o0;
    *(us8*)(dst + 8) = o1;
  }
}

// --------------------------------------------------------- rel-pos einsums ---
__global__ void k_relh(const u16* __restrict__ Qh, const u16* __restrict__ Ql,
                       const float* __restrict__ rp, float* __restrict__ R){
  __shared__ float qs[64][68];
  __shared__ float rs[64][68];
  int h = blockIdx.y, qh = blockIdx.x;
  int t = threadIdx.x;
  {
    int r = t >> 2, c0 = (t & 3) * 16;
    size_t qb = ((size_t)h * NTOK + qh*64 + r) * 64 + c0;
#pragma unroll
    for (int j = 0; j < 2; ++j){
      us8 vh = *(const us8*)(Qh + qb + j*8);
      us8 vl = *(const us8*)(Ql + qb + j*8);
#pragma unroll
      for (int e = 0; e < 8; ++e)
        qs[r][c0 + j*8 + e] = bf2f(vh[e]) + bf2f(vl[e]);
    }
    const float* pr = rp + (size_t)(qh - r + 63) * 64 + c0;
#pragma unroll
    for (int j = 0; j < 4; ++j){
      f4v v = *(const f4v*)(pr + j*4);
      rs[r][c0+j*4+0]=v[0]; rs[r][c0+j*4+1]=v[1];
      rs[r][c0+j*4+2]=v[2]; rs[r][c0+j*4+3]=v[3];
    }
  }
  __syncthreads();
  int qw = t >> 2, k0 = t & 3;
  float acc[16] = {};
  for (int c = 0; c < 64; c += 4){
    f4v qv = *(const f4v*)(&qs[qw][c]);
#pragma unroll
    for (int i = 0; i < 16; ++i){
      f4v rv = *(const f4v*)(&rs[k0 + 4*i][c]);
      acc[i] += qv[0]*rv[0] + qv[1]*rv[1] + qv[2]*rv[2] + qv[3]*rv[3];
    }
  }
  float* o = R + ((size_t)h * NTOK + qh*64 + qw) * 64;
#pragma unroll
  for (int i = 0; i < 16; ++i) o[k0 + 4*i] = acc[i] * LOG2E_F;
}

__global__ void k_relw(const u16* __restrict__ Qh, const u16* __restrict__ Ql,
                       const float* __restrict__ rp, float* __restrict__ R){
  __shared__ float qs[64][68];   // [qh][c]
  __shared__ float rs[64][68];   // [kw][c]
  int h = blockIdx.y, qw = blockIdx.x;
  int t = threadIdx.x;
  {
    int r = t >> 2, c0 = (t & 3) * 16;
    size_t qb = ((size_t)h * NTOK + r*64 + qw) * 64 + c0;
#pragma unroll
    for (int j = 0; j < 2; ++j){
      us8 vh = *(const us8*)(Qh + qb + j*8);
      us8 vl = *(const us8*)(Ql + qb + j*8);
#pragma unroll
      for (int e = 0; e < 8; ++e)
        qs[r][c0 + j*8 + e] = bf2f(vh[e]) + bf2f(vl[e]);
    }
    const float* pr = rp + (size_t)(qw - r + 63) * 64 + c0;
#pragma unroll
    for (int j = 0; j < 4; ++j){
      f4v v = *(const f4v*)(pr + j*4);
      rs[r][c0+j*4+0]=v[0]; rs[r][c0+j*4+1]=v[1];
      rs[r][c0+j*4+2]=v[2]; rs[r][c0+j*4+3]=v[3];
    }
  }
  __syncthreads();
  int qh = t >> 2, k0 = t & 3;
  float acc[16] = {};
  for (int c = 0; c < 64; c += 4){
    f4v qv = *(const f4v*)(&qs[qh][c]);
#pragma unroll
    for (int i = 0; i < 16; ++i){
      f4v rv = *(const f4v*)(&rs[k0 + 4*i][c]);
      acc[i] += qv[0]*rv[0] + qv[1]*rv[1] + qv[2]*rv[2] + qv[3]*rv[3];
    }
  }
  float* o = R + ((size_t)h * NTOK + qh*64 + qw) * 64;
#pragma unroll
  for (int i = 0; i < 16; ++i) o[k0 + 4*i] = acc[i] * LOG2E_F;
}

// --------------------------------------------------------- flash attention ---
// R7 structure (best measured: 161.5us). grid (64 q-tiles, 12 heads),
// 4 waves x 16 q-rows, KV tile = 64. SWAPPED operands: S^T = mfma(K, Q);
// softmax state scalar per lane. T14 async-STAGE split, single buffer.
// R11 change: QK^T 6-deep MFMA chain split into 2x3 (a1,a2) -> 8 indep
// chains across tt, testing H1 (MFMA dep-latency serialization).
// LDS: Kh[8K]@0, Kl@8192, Vt@16384 (xor ((row&7)<<4)), P@24576+wid*2304.
__global__ __launch_bounds__(256)
void k_attn(const u16* __restrict__ Qh, const u16* __restrict__ Ql,
            const u16* __restrict__ Kh, const u16* __restrict__ Kl,
            const u16* __restrict__ Vth,
            const float* __restrict__ Rh, const float* __restrict__ Rw,
            u16* __restrict__ Oh, u16* __restrict__ Ol)
{
  __shared__ __align__(16) unsigned char sm[33792];
  const int t = threadIdx.x;
  const int lane = t & 63, wid = t >> 6;
  const int l15 = lane & 15, g = lane >> 4;
  const int h = blockIdx.y;
  const int qrow0 = blockIdx.x * 64 + wid * 16;

  // staging pointers (xor-swizzled source, linear LDS dest = ch*4096 + t*16)
  const char* kGh[2]; const char* kGl[2]; const char* vG[2];
#pragma unroll
  for (int ch = 0; ch < 2; ++ch){
    int p = ch * 4096 + t * 16;
    int row = p >> 7;
    int cb  = (p & 127) ^ ((row & 7) << 4);
    kGh[ch] = (const char*)Kh + ((size_t)h * NTOK + row) * 128 + cb;
    kGl[ch] = (const char*)Kl + ((size_t)h * NTOK + row) * 128 + cb;
    vG[ch]  = (const char*)Vth + ((size_t)h * 64 + row) * (NTOK*2) + cb;
  }

  // Q fragments (B-operand; row = q = l15, d = g*8+e), held all kernel
  const size_t qoff = ((size_t)h * NTOK + qrow0 + l15) * 64 + g * 8;
  s8v qh0 = *(const s8v*)(Qh + qoff);
  s8v qh1 = *(const s8v*)(Qh + qoff + 32);
  s8v ql0 = *(const s8v*)(Ql + qoff);
  s8v ql1 = *(const s8v*)(Ql + qoff + 32);

  // K/V LDS read bases
  const int xr  = (l15 & 7) << 4;
  const int kb0 = l15 * 128 + ((g * 16)      ^ xr);
  const int kb1 = l15 * 128 + ((g * 16 + 64) ^ xr);
  const int vb0 = 16384 + kb0;
  const int vb1 = 16384 + kb1;
  const int pbase = 24576 + wid * 2304 + l15 * 144;

  // rel_w hoist (iteration-invariant); rel_h read per-iter from global (L2/L3)
  const float* rwp = Rw + ((size_t)h * NTOK + qrow0 + l15) * 64 + 4*g;
  f4v rwv[4];
#pragma unroll
  for (int tt = 0; tt < 4; ++tt) rwv[tt] = *(const f4v*)(rwp + 16*tt);
  const float* rhp = Rh + ((size_t)h * NTOK + qrow0 + l15) * 64;

  // T14 reg-staged tile: 6 x 16B per thread
  f4v st[6];
  auto do_loads = [&](){
    st[0] = *(const f4v*)kGh[0]; st[1] = *(const f4v*)kGh[1];
    st[2] = *(const f4v*)kGl[0]; st[3] = *(const f4v*)kGl[1];
    st[4] = *(const f4v*)vG[0];  st[5] = *(const f4v*)vG[1];
    kGh[0] += 8192; kGh[1] += 8192;
    kGl[0] += 8192; kGl[1] += 8192;
    vG[0]  += 128;  vG[1]  += 128;
  };
  auto do_writes = [&](){
    *(f4v*)(sm + 0     +    0 + t*16) = st[0];
    *(f4v*)(sm + 0     + 4096 + t*16) = st[1];
    *(f4v*)(sm + 8192  +    0 + t*16) = st[2];
    *(f4v*)(sm + 8192  + 4096 + t*16) = st[3];
    *(f4v*)(sm + 16384 +    0 + t*16) = st[4];
    *(f4v*)(sm + 16384 + 4096 + t*16) = st[5];
  };

  // prologue: tile 0 -> LDS; tile 1 loads in flight
  do_loads();
  do_writes();
  do_loads();
  asm volatile("s_waitcnt lgkmcnt(0)" ::: "memory");
  hard_barrier();

  f4v o[4] = {};
  float m2 = -1.0e30f, ls = 0.f;

  for (int it = 0; it < 64; ++it){
    const float rhv = rhp[it];   // rel_h: scalar per lane per iteration

    // S^T = K Q^T (split: hh, hl, lh). s[t][r] = S[k=16t+4g+r][q=l15]
    // R11: two 3-deep chains per tt (8 independent chains total).
    f4v s[4];
    __builtin_amdgcn_s_setprio(1);
#pragma unroll
    for (int tt = 0; tt < 4; ++tt){
      s8v kh_0 = *(const s8v*)(sm + kb0 + tt*2048);
      s8v kh_1 = *(const s8v*)(sm + kb1 + tt*2048);
      s8v kl_0 = *(const s8v*)(sm + kb0 + tt*2048 + 8192);
      s8v kl_1 = *(const s8v*)(sm + kb1 + tt*2048 + 8192);
      f4v a1 = {}, a2 = {};
      a1 = MFMA16(kh_0, qh0, a1);
      a2 = MFMA16(kh_1, qh1, a2);
      a1 = MFMA16(kl_0, qh0, a1);
      a2 = MFMA16(kl_1, qh1, a2);
      a1 = MFMA16(kh_0, ql0, a1);
      a2 = MFMA16(kh_1, ql1, a2);
      s[tt] = a1 + a2;
    }
    __builtin_amdgcn_s_setprio(0);

    // bias + row max (all 16 values belong to q-row l15)
    float pm = -1.0e30f;
#pragma unroll
    for (int tt = 0; tt < 4; ++tt){
#pragma unroll
      for (int r = 0; r < 4; ++r){
        s[tt][r] += rhv + rwv[tt][r];
        pm = fmaxf(pm, s[tt][r]);
      }
    }
    pm = fmaxf(pm, __shfl_xor(pm, 16, 64));
    pm = fmaxf(pm, __shfl_xor(pm, 32, 64));
    const float mn = fmaxf(m2, pm);
    const float fr = EXP2(m2 - mn);
    m2 = mn;
    float ps = 0.f;
#pragma unroll
    for (int tt = 0; tt < 4; ++tt){
#pragma unroll
      for (int r = 0; r < 4; ++r){
        float p = EXP2(s[tt][r] - m2);
        s[tt][r] = p;
        ps += p;
      }
    }
    ps += __shfl_xor(ps, 16, 64);
    ps += __shfl_xor(ps, 32, 64);
    ls = ls * fr + ps;

    // P -> LDS (wave-private region, no barrier needed)
#pragma unroll
    for (int tt = 0; tt < 4; ++tt){
      u32x2 w2;
      w2[0] = cvtpk(s[tt][0], s[tt][1]);
      w2[1] = cvtpk(s[tt][2], s[tt][3]);
      *(u32x2*)(sm + pbase + 8*g + 32*tt) = w2;
    }
    // rescale O (scalar factor: accumulator is q-row-local)
#pragma unroll
    for (int dt = 0; dt < 4; ++dt){
#pragma unroll
      for (int r = 0; r < 4; ++r) o[dt][r] *= fr;
    }
    // O^T += Vt @ P^T
    s8v pa0 = *(const s8v*)(sm + pbase + 16*g);
    s8v pa1 = *(const s8v*)(sm + pbase + 16*g + 64);
    __builtin_amdgcn_s_setprio(1);
#pragma unroll
    for (int dt = 0; dt < 4; ++dt){
      s8v v0 = *(const s8v*)(sm + vb0 + dt*2048);
      s8v v1 = *(const s8v*)(sm + vb1 + dt*2048);
      o[dt] = MFMA16(v0, pa0, o[dt]);
      o[dt] = MFMA16(v1, pa1, o[dt]);
    }
    __builtin_amdgcn_s_setprio(0);

    hard_barrier();          // A: all waves done reading tile it
    if (it < 63){
      do_writes();           // tile it+1 -> LDS (compiler waits the loads)
      if (it < 62) do_loads();   // tile it+2 -> regs, in flight across B
    }
    asm volatile("s_waitcnt lgkmcnt(0)" ::: "memory");
    hard_barrier();          // B: writes visible to all waves
  }

  // epilogue: o[dt][r] = O[q = qrow0+l15][d = 16dt + 4g + r]; fused hi/lo split
  const float inv = 1.0f / ls;
  const size_t obase = (size_t)(qrow0 + l15) * DM + h*64 + 4*g;
#pragma unroll
  for (int dt = 0; dt < 4; ++dt){
    us4 hv, lv;
#pragma unroll
    for (int r = 0; r < 4; ++r){
      float v = o[dt][r] * inv;
      u16 hb = f2bf(v);
      hv[r] = hb;
      lv[r] = f2bf(v - bf2f(hb));
    }
    *(us4*)(Oh + obase + 16*dt) = hv;
    *(us4*)(Ol + obase + 16*dt) = lv;
  }
}

// ------------------------------------------------------------------- host ---
extern "C" void kernel_launch(void* const* d_in, const int* in_sizes, int n_in,
                              void* d_out, int out_size, void* d_ws, size_t ws_size,
                              hipStream_t stream){
  (void)in_sizes; (void)n_in; (void)out_size; (void)ws_size;
  const float* x      = (const float*)d_in[0];
  const float* w_qkv  = (const float*)d_in[1];
  const float* b_qkv  = (const float*)d_in[2];
  const float* w_proj = (const float*)d_in[3];
  const float* b_proj = (const float*)d_in[4];
  const float* rph    = (const float*)d_in[5];
  const float* rpw    = (const float*)d_in[6];
  float* out = (float*)d_out;

  char* w = (char*)d_ws;
  size_t off = 0;
  auto nxt = [&](size_t b) -> char* {
    char* p = w + off; off += (b + 255) & ~(size_t)255; return p;
  };
  u16*   Xh  = (u16*)  nxt((size_t)NTOK*DM*2);
  u16*   Xl  = (u16*)  nxt((size_t)NTOK*DM*2);
  u16*   Wqh = (u16*)  nxt((size_t)3*DM*DM*2);
  u16*   Wql = (u16*)  nxt((size_t)3*DM*DM*2);
  u16*   Wph = (u16*)  nxt((size_t)DM*DM*2);
  u16*   Wpl = (u16*)  nxt((size_t)DM*DM*2);
  u16*   Qh  = (u16*)  nxt((size_t)NTOK*DM*2);
  u16*   Ql  = (u16*)  nxt((size_t)NTOK*DM*2);
  u16*   Kh  = (u16*)  nxt((size_t)NTOK*DM*2);
  u16*   Kl  = (u16*)  nxt((size_t)NTOK*DM*2);
  float* Vf  = (float*)nxt((size_t)NTOK*DM*4);
  u16*   Vth = (u16*)  nxt((size_t)NTOK*DM*2);
  float* Rh  = (float*)nxt((size_t)12*NTOK*64*4);
  float* Rw  = (float*)nxt((size_t)12*NTOK*64*4);
  u16*   Oh  = Xh;                                    // X dead after G1
  u16*   Ol  = Xl;

  k_split3<<<dim3(2048), dim3(256), 0, stream>>>(
      x,      Xh,  Xl,  NTOK*DM/4,
      w_qkv,  Wqh, Wql, 3*DM*DM/4,
      w_proj, Wph, Wpl, DM*DM/4);

  k_gemm<1><<<dim3(18, 32), dim3(256), 0, stream>>>(
      Xh, Xl, Wqh, Wql, b_qkv, DM, Qh, Ql, Kh, Kl, Vf, nullptr);

  k_vtrans<<<dim3(64, 12), dim3(256), 0, stream>>>(Vf, Vth);
  k_relh  <<<dim3(64, 12), dim3(256), 0, stream>>>(Qh, Ql, rph, Rh);
  k_relw  <<<dim3(64, 12), dim3(256), 0, stream>>>(Qh, Ql, rpw, Rw);

  k_attn<<<dim3(64, 12), dim3(256), 0, stream>>>(Qh, Ql, Kh, Kl, Vth, Rh, Rw, Oh, Ol);

  k_gemm<2><<<dim3(6, 32), dim3(256), 0, stream>>>(
      Oh, Ol, Wph, Wpl, b_proj, DM,
      nullptr, nullptr, nullptr, nullptr, nullptr, out);
}